// Round 9
// baseline (47.811 us; speedup 1.0000x reference)
//
#include <hip/hip_runtime.h>
#include <hip/hip_bf16.h>
#include <math.h>

// max_{n,m} ||L[n]-R[m]||, L,R: [8192][64] fp32.
// R9: MEASUREMENT ROUND. Identical R6 main kernel, launched 3x (idempotent:
// atomicMax on sqrt'd block max). Delta vs R6 total isolates warm main-kernel
// cost: total ~= fixed + prepack + main_cold + 2*main_warm. Also drops the
// finalize kernel (sqrt+atomicMax fused into main tail; prepack zeroes d_out).

typedef __attribute__((ext_vector_type(8)))  short  short8;   // bf16x8 frag
typedef __attribute__((ext_vector_type(4)))  float  f32x4;
typedef __attribute__((ext_vector_type(16))) float  f32x16;   // 32x32 accum

constexpr int D  = 64;
constexpr int NR = 8192;

__device__ __forceinline__ short f2bf(float f) {
    __hip_bfloat16 h = __float2bfloat16(f);
    return __builtin_bit_cast(short, h);
}

// Frag-packed layout: row r, k-chunk kk (16 k's), k-half kh, elem e:
//   short index = ((r>>5)*4 + kk)*512 + (kh*32 + (r&31))*8 + e

// ---- prepack: 1 thread per (row, 8-float half-chunk); 8 threads/row ----
__global__ __launch_bounds__(256) void prepack_kernel(
    const float* __restrict__ L, const float* __restrict__ R,
    short* __restrict__ Apk, short* __restrict__ Bpk,
    float* __restrict__ lsq, float* __restrict__ rsq,
    unsigned int* __restrict__ outbits)
{
    const int t = blockIdx.x * 256 + threadIdx.x;   // 0..131071
    const int r = t >> 3;                           // 0..16383
    const int j = t & 7;                            // half-chunk
    const int kk = j >> 1, kh = j & 1;
    const bool isL = (r < NR);
    const int rr = isL ? r : r - NR;

    const float* src = (isL ? L : R) + (size_t)rr * D + j * 8;
    short* pk = isL ? Apk : Bpk;

    f32x4 v0 = *reinterpret_cast<const f32x4*>(src + 0);
    f32x4 v1 = *reinterpret_cast<const f32x4*>(src + 4);

    float p = 0.f;
    #pragma unroll
    for (int e = 0; e < 4; ++e) { p = fmaf(v0[e], v0[e], p); p = fmaf(v1[e], v1[e], p); }

    short8 w;
    #pragma unroll
    for (int e = 0; e < 4; ++e) { w[e] = f2bf(v0[e]); w[4+e] = f2bf(v1[e]); }
    *reinterpret_cast<short8*>(
        pk + ((size_t)(rr >> 5) * 4 + kk) * 512 + (kh * 32 + (rr & 31)) * 8) = w;

    p += __shfl_xor(p, 1, 64);
    p += __shfl_xor(p, 2, 64);
    p += __shfl_xor(p, 4, 64);
    if (j == 0) (isL ? lsq : rsq)[rr] = p;

    if (t == 0) *outbits = 0u;   // zero d_out (harness poisons 0xAA)
}

// ---- main (R6 structure, verbatim): 4 waves (2x2), block 128m x 256n,
// 4-tile m-loop, A LDS-dbuf via global_load_lds, B split regs/LDS ----
__global__ __launch_bounds__(256, 2) void pairdist_mfma_kernel(
    const short* __restrict__ Apk, const short* __restrict__ Bpk,
    const float* __restrict__ lsq, const float* __restrict__ rsq,
    unsigned int* __restrict__ outbits)
{
    __shared__ __align__(16) short A_lds[2][4][4][64][8];  // 2 x 16 KiB
    __shared__ __align__(16) short B_lds[4][4][64][8];     // 16 KiB (groups {2,3,6,7})
    __shared__ __align__(16) float lsq_s[512];
    __shared__ __align__(16) float rsq_s[256];
    __shared__ float wmax_s[4];

    const int tid  = threadIdx.x;
    const int lane = tid & 63;
    const int wave = tid >> 6;
    const int xc = blockIdx.x;     // 0..15 -> 512-row chunk of L
    const int yb = blockIdx.y;     // 0..31 -> 256-col chunk of R

    const size_t Abase = (size_t)(xc * 16) * 2048;

    {
        const short* At = Apk + Abase;
        #pragma unroll
        for (int i = 0; i < 4; ++i)
            __builtin_amdgcn_global_load_lds(
                (const __attribute__((address_space(1))) unsigned int*)
                    (At + ((size_t)i * 4 + wave) * 512 + lane * 8),
                (__attribute__((address_space(3))) unsigned int*)
                    (&A_lds[0][i][wave][0][0]),
                16, 0, 0);
    }
    {
        #pragma unroll
        for (int s = 0; s < 4; ++s) {
            const int gsrc = yb * 8 + (s >> 1) * 4 + 2 + (s & 1);
            __builtin_amdgcn_global_load_lds(
                (const __attribute__((address_space(1))) unsigned int*)
                    (Bpk + ((size_t)gsrc * 4 + wave) * 512 + lane * 8),
                (__attribute__((address_space(3))) unsigned int*)
                    (&B_lds[s][wave][0][0]),
                16, 0, 0);
        }
    }

    lsq_s[tid]       = lsq[xc * 512 + tid];
    lsq_s[256 + tid] = lsq[xc * 512 + 256 + tid];
    rsq_s[tid]       = rsq[yb * 256 + tid];

    const int wm = wave >> 1;
    const int wn = wave & 1;
    short8 bf[2][4];
    #pragma unroll
    for (int nj = 0; nj < 2; ++nj)
        #pragma unroll
        for (int kk = 0; kk < 4; ++kk)
            bf[nj][kk] = *reinterpret_cast<const short8*>(
                Bpk + ((size_t)(yb * 8 + wn * 4 + nj) * 4 + kk) * 512 + lane * 8);

    __syncthreads();

    const int col = lane & 31;
    const int h   = lane >> 5;
    float rq[4];
    #pragma unroll
    for (int nj = 0; nj < 4; ++nj) rq[nj] = rsq_s[wn * 128 + nj * 32 + col];

    float lmax = 0.f;
    int cur = 0;
    for (int t = 0; t < 4; ++t) {
        if (t < 3) {
            const short* At = Apk + Abase + (size_t)(t + 1) * 8192;
            #pragma unroll
            for (int i = 0; i < 4; ++i)
                __builtin_amdgcn_global_load_lds(
                    (const __attribute__((address_space(1))) unsigned int*)
                        (At + ((size_t)i * 4 + wave) * 512 + lane * 8),
                    (__attribute__((address_space(3))) unsigned int*)
                        (&A_lds[cur ^ 1][i][wave][0][0]),
                    16, 0, 0);
            __builtin_amdgcn_sched_barrier(0);
        }

        f32x16 acc[2][4] = {};
        #pragma unroll
        for (int kk = 0; kk < 4; ++kk) {
            short8 a0 = *reinterpret_cast<const short8*>(&A_lds[cur][wm*2+0][kk][lane][0]);
            short8 a1 = *reinterpret_cast<const short8*>(&A_lds[cur][wm*2+1][kk][lane][0]);
            short8 b2 = *reinterpret_cast<const short8*>(&B_lds[wn*2+0][kk][lane][0]);
            short8 b3 = *reinterpret_cast<const short8*>(&B_lds[wn*2+1][kk][lane][0]);
            acc[0][0] = __builtin_amdgcn_mfma_f32_32x32x16_bf16(a0, bf[0][kk], acc[0][0], 0, 0, 0);
            acc[0][1] = __builtin_amdgcn_mfma_f32_32x32x16_bf16(a0, bf[1][kk], acc[0][1], 0, 0, 0);
            acc[0][2] = __builtin_amdgcn_mfma_f32_32x32x16_bf16(a0, b2,        acc[0][2], 0, 0, 0);
            acc[0][3] = __builtin_amdgcn_mfma_f32_32x32x16_bf16(a0, b3,        acc[0][3], 0, 0, 0);
            acc[1][0] = __builtin_amdgcn_mfma_f32_32x32x16_bf16(a1, bf[0][kk], acc[1][0], 0, 0, 0);
            acc[1][1] = __builtin_amdgcn_mfma_f32_32x32x16_bf16(a1, bf[1][kk], acc[1][1], 0, 0, 0);
            acc[1][2] = __builtin_amdgcn_mfma_f32_32x32x16_bf16(a1, b2,        acc[1][2], 0, 0, 0);
            acc[1][3] = __builtin_amdgcn_mfma_f32_32x32x16_bf16(a1, b3,        acc[1][3], 0, 0, 0);
        }

        #pragma unroll
        for (int mi = 0; mi < 2; ++mi) {
            const int rbase = t * 128 + (wm * 2 + mi) * 32 + 4 * h;
            f32x4 lq[4];
            lq[0] = *reinterpret_cast<const f32x4*>(&lsq_s[rbase +  0]);
            lq[1] = *reinterpret_cast<const f32x4*>(&lsq_s[rbase +  8]);
            lq[2] = *reinterpret_cast<const f32x4*>(&lsq_s[rbase + 16]);
            lq[3] = *reinterpret_cast<const f32x4*>(&lsq_s[rbase + 24]);
            #pragma unroll
            for (int nj = 0; nj < 4; ++nj) {
                float x[16];
                #pragma unroll
                for (int g = 0; g < 4; ++g)
                    #pragma unroll
                    for (int e = 0; e < 4; ++e)
                        x[g*4+e] = fmaf(-2.f, acc[mi][nj][g*4+e], lq[g][e]);
                float y0 = fmaxf(x[0],  x[1]),  y1 = fmaxf(x[2],  x[3]);
                float y2 = fmaxf(x[4],  x[5]),  y3 = fmaxf(x[6],  x[7]);
                float y4 = fmaxf(x[8],  x[9]),  y5 = fmaxf(x[10], x[11]);
                float y6 = fmaxf(x[12], x[13]), y7 = fmaxf(x[14], x[15]);
                float z0 = fmaxf(y0, y1), z1 = fmaxf(y2, y3);
                float z2 = fmaxf(y4, y5), z3 = fmaxf(y6, y7);
                float m  = fmaxf(fmaxf(z0, z1), fmaxf(z2, z3));
                lmax = fmaxf(lmax, m + rq[nj]);
            }
        }

        __syncthreads();
        cur ^= 1;
    }

    #pragma unroll
    for (int off = 32; off >= 1; off >>= 1)
        lmax = fmaxf(lmax, __shfl_xor(lmax, off, 64));
    if (lane == 0) wmax_s[wave] = lmax;
    __syncthreads();
    if (tid == 0) {
        float bmax = fmaxf(fmaxf(wmax_s[0], wmax_s[1]), fmaxf(wmax_s[2], wmax_s[3]));
        bmax = sqrtf(fmaxf(bmax, 0.f));            // sqrt monotone
        atomicMax(outbits, __float_as_uint(bmax)); // idempotent across reruns
    }
}

extern "C" void kernel_launch(void* const* d_in, const int* in_sizes, int n_in,
                              void* d_out, int out_size, void* d_ws, size_t ws_size,
                              hipStream_t stream) {
    const float* L = (const float*)d_in[0];
    const float* R = (const float*)d_in[1];

    short* Apk = (short*)d_ws;
    short* Bpk = Apk + (size_t)NR * D;           // 524288 shorts each
    float* lsqg = (float*)(Bpk + (size_t)NR * D);
    float* rsqg = lsqg + NR;
    unsigned int* outbits = (unsigned int*)d_out;

    prepack_kernel<<<(2 * NR * 8) / 256, 256, 0, stream>>>(L, R, Apk, Bpk, lsqg, rsqg, outbits);
    // 3x identical main launches: #2 and #3 are warm and idempotent.
    // Delta vs single-launch totals isolates the warm main-kernel cost.
    pairdist_mfma_kernel<<<dim3(16, 32), dim3(256), 0, stream>>>(Apk, Bpk, lsqg, rsqg, outbits);
    pairdist_mfma_kernel<<<dim3(16, 32), dim3(256), 0, stream>>>(Apk, Bpk, lsqg, rsqg, outbits);
    pairdist_mfma_kernel<<<dim3(16, 32), dim3(256), 0, stream>>>(Apk, Bpk, lsqg, rsqg, outbits);
}

// Round 10
// 23.265 us; speedup vs baseline: 2.0550x; 2.0550x over previous
//
#include <hip/hip_runtime.h>
#include <hip/hip_bf16.h>
#include <math.h>

// max_{n,m} ||L[n]-R[m]||, L,R: [8192][64] fp32.
// R10: single-stage, zero-barrier main loop. A (512 rows, 64KB) staged ONCE
// via global_load_lds; B entirely in registers (reused across all 4 m-tiles);
// norms read direct from global (L1 broadcast). No barriers / no VMEM in the
// 4-tile MFMA loop. Tail reduce reuses dead A_lds; sqrt+atomicMax into d_out.

typedef __attribute__((ext_vector_type(8)))  short  short8;   // bf16x8 frag
typedef __attribute__((ext_vector_type(4)))  float  f32x4;
typedef __attribute__((ext_vector_type(16))) float  f32x16;   // 32x32 accum

constexpr int D  = 64;
constexpr int NR = 8192;

__device__ __forceinline__ short f2bf(float f) {
    __hip_bfloat16 h = __float2bfloat16(f);
    return __builtin_bit_cast(short, h);
}

// Frag-packed layout: row r, k-chunk kk (16 k's), k-half kh, elem e:
//   short index = ((r>>5)*4 + kk)*512 + (kh*32 + (r&31))*8 + e

// ---- prepack: 1 thread per (row, 8-float half-chunk); 8 threads/row ----
__global__ __launch_bounds__(256) void prepack_kernel(
    const float* __restrict__ L, const float* __restrict__ R,
    short* __restrict__ Apk, short* __restrict__ Bpk,
    float* __restrict__ lsq, float* __restrict__ rsq,
    unsigned int* __restrict__ outbits)
{
    const int t = blockIdx.x * 256 + threadIdx.x;   // 0..131071
    const int r = t >> 3;                           // 0..16383
    const int j = t & 7;                            // half-chunk
    const int kk = j >> 1, kh = j & 1;
    const bool isL = (r < NR);
    const int rr = isL ? r : r - NR;

    const float* src = (isL ? L : R) + (size_t)rr * D + j * 8;
    short* pk = isL ? Apk : Bpk;

    f32x4 v0 = *reinterpret_cast<const f32x4*>(src + 0);
    f32x4 v1 = *reinterpret_cast<const f32x4*>(src + 4);

    float p = 0.f;
    #pragma unroll
    for (int e = 0; e < 4; ++e) { p = fmaf(v0[e], v0[e], p); p = fmaf(v1[e], v1[e], p); }

    short8 w;
    #pragma unroll
    for (int e = 0; e < 4; ++e) { w[e] = f2bf(v0[e]); w[4+e] = f2bf(v1[e]); }
    *reinterpret_cast<short8*>(
        pk + ((size_t)(rr >> 5) * 4 + kk) * 512 + (kh * 32 + (rr & 31)) * 8) = w;

    p += __shfl_xor(p, 1, 64);
    p += __shfl_xor(p, 2, 64);
    p += __shfl_xor(p, 4, 64);
    if (j == 0) (isL ? lsq : rsq)[rr] = p;

    if (t == 0) *outbits = 0u;   // zero d_out (harness poisons 0xAA)
}

// ---- main: 4 waves (2m x 2n), block 512m x 256n (4 m-tiles of 128) ----
// grid (16, 32) = 512 blocks, 2 resident/CU.
__global__ __launch_bounds__(256, 2) void pairdist_mfma_kernel(
    const short* __restrict__ Apk, const short* __restrict__ Bpk,
    const float* __restrict__ lsq, const float* __restrict__ rsq,
    unsigned int* __restrict__ outbits)
{
    __shared__ __align__(16) short A_lds[16][4][64][8];   // exactly 64 KiB

    const int tid  = threadIdx.x;
    const int lane = tid & 63;
    const int wave = tid >> 6;
    const int xc = blockIdx.x;     // 0..15 -> 512-row chunk of L
    const int yb = blockIdx.y;     // 0..31 -> 256-col chunk of R

    // ---- stage ALL of A for this block: 64 x 1KB global_load_lds, once ----
    {
        const short* At = Apk + (size_t)(xc * 16) * 2048;
        short* Al = &A_lds[0][0][0][0];
        #pragma unroll
        for (int i = 0; i < 16; ++i) {
            const int off = (i * 4 + wave) * 512;
            __builtin_amdgcn_global_load_lds(
                (const __attribute__((address_space(1))) unsigned int*)(At + off + lane * 8),
                (__attribute__((address_space(3))) unsigned int*)(Al + off),
                16, 0, 0);
        }
    }

    const int wm = wave >> 1;      // 64-row half of each 128-row tile
    const int wn = wave & 1;       // 128-col half of 256
    // ---- B-frags for this wave's 128 cols, all K: 16 x dwordx4, in VGPRs ----
    short8 bf[4][4];
    #pragma unroll
    for (int nj = 0; nj < 4; ++nj)
        #pragma unroll
        for (int kk = 0; kk < 4; ++kk)
            bf[nj][kk] = *reinterpret_cast<const short8*>(
                Bpk + ((size_t)(yb * 8 + wn * 4 + nj) * 4 + kk) * 512 + lane * 8);

    const int col = lane & 31;
    const int h   = lane >> 5;
    float rq[4];
    #pragma unroll
    for (int nj = 0; nj < 4; ++nj)
        rq[nj] = rsq[yb * 256 + wn * 128 + nj * 32 + col];

    __syncthreads();   // A staged; only barrier before the tail reduce

    float lmax = 0.f;
    #pragma unroll
    for (int t = 0; t < 4; ++t) {
        // per-tile lsq fragments, direct from global (2 distinct addrs/wave -> L1)
        f32x4 lqv[2][4];
        #pragma unroll
        for (int mi = 0; mi < 2; ++mi) {
            const int rbase = xc * 512 + t * 128 + (wm * 2 + mi) * 32 + 4 * h;
            #pragma unroll
            for (int g = 0; g < 4; ++g)
                lqv[mi][g] = *reinterpret_cast<const f32x4*>(lsq + rbase + g * 8);
        }

        f32x16 acc[2][4] = {};
        #pragma unroll
        for (int kk = 0; kk < 4; ++kk) {
            short8 a0 = *reinterpret_cast<const short8*>(&A_lds[t*4 + wm*2 + 0][kk][lane][0]);
            short8 a1 = *reinterpret_cast<const short8*>(&A_lds[t*4 + wm*2 + 1][kk][lane][0]);
            acc[0][0] = __builtin_amdgcn_mfma_f32_32x32x16_bf16(a0, bf[0][kk], acc[0][0], 0, 0, 0);
            acc[0][1] = __builtin_amdgcn_mfma_f32_32x32x16_bf16(a0, bf[1][kk], acc[0][1], 0, 0, 0);
            acc[0][2] = __builtin_amdgcn_mfma_f32_32x32x16_bf16(a0, bf[2][kk], acc[0][2], 0, 0, 0);
            acc[0][3] = __builtin_amdgcn_mfma_f32_32x32x16_bf16(a0, bf[3][kk], acc[0][3], 0, 0, 0);
            acc[1][0] = __builtin_amdgcn_mfma_f32_32x32x16_bf16(a1, bf[0][kk], acc[1][0], 0, 0, 0);
            acc[1][1] = __builtin_amdgcn_mfma_f32_32x32x16_bf16(a1, bf[1][kk], acc[1][1], 0, 0, 0);
            acc[1][2] = __builtin_amdgcn_mfma_f32_32x32x16_bf16(a1, bf[2][kk], acc[1][2], 0, 0, 0);
            acc[1][3] = __builtin_amdgcn_mfma_f32_32x32x16_bf16(a1, bf[3][kk], acc[1][3], 0, 0, 0);
        }

        // epilogue: sq = lsq[row] + rsq[col] - 2*dot, balanced max tree.
        // C layout (32x32): col = lane&31, row = (r&3) + 8*(r>>2) + 4*(lane>>5)
        #pragma unroll
        for (int mi = 0; mi < 2; ++mi) {
            #pragma unroll
            for (int nj = 0; nj < 4; ++nj) {
                float x[16];
                #pragma unroll
                for (int g = 0; g < 4; ++g)
                    #pragma unroll
                    for (int e = 0; e < 4; ++e)
                        x[g*4+e] = fmaf(-2.f, acc[mi][nj][g*4 + e], lqv[mi][g][e]);
                float y0 = fmaxf(x[0],  x[1]),  y1 = fmaxf(x[2],  x[3]);
                float y2 = fmaxf(x[4],  x[5]),  y3 = fmaxf(x[6],  x[7]);
                float y4 = fmaxf(x[8],  x[9]),  y5 = fmaxf(x[10], x[11]);
                float y6 = fmaxf(x[12], x[13]), y7 = fmaxf(x[14], x[15]);
                float z0 = fmaxf(y0, y1), z1 = fmaxf(y2, y3);
                float z2 = fmaxf(y4, y5), z3 = fmaxf(y6, y7);
                float m  = fmaxf(fmaxf(z0, z1), fmaxf(z2, z3));
                lmax = fmaxf(lmax, m + rq[nj]);
            }
        }
    }

    // ---- tail: wave butterfly, block reduce via dead A_lds, one atomic ----
    #pragma unroll
    for (int off = 32; off >= 1; off >>= 1)
        lmax = fmaxf(lmax, __shfl_xor(lmax, off, 64));

    __syncthreads();   // all A_lds reads complete -> safe to reuse as scratch
    float* wmax = reinterpret_cast<float*>(&A_lds[0][0][0][0]);
    if (lane == 0) wmax[wave] = lmax;
    __syncthreads();
    if (tid == 0) {
        float bmax = fmaxf(fmaxf(wmax[0], wmax[1]), fmaxf(wmax[2], wmax[3]));
        bmax = sqrtf(fmaxf(bmax, 0.f));            // sqrt monotone
        atomicMax(outbits, __float_as_uint(bmax)); // uint order == float order, >=0
    }
}

extern "C" void kernel_launch(void* const* d_in, const int* in_sizes, int n_in,
                              void* d_out, int out_size, void* d_ws, size_t ws_size,
                              hipStream_t stream) {
    const float* L = (const float*)d_in[0];
    const float* R = (const float*)d_in[1];

    short* Apk = (short*)d_ws;
    short* Bpk = Apk + (size_t)NR * D;           // 524288 shorts each
    float* lsqg = (float*)(Bpk + (size_t)NR * D);
    float* rsqg = lsqg + NR;
    unsigned int* outbits = (unsigned int*)d_out;

    prepack_kernel<<<(2 * NR * 8) / 256, 256, 0, stream>>>(L, R, Apk, Bpk, lsqg, rsqg, outbits);
    pairdist_mfma_kernel<<<dim3(16, 32), dim3(256), 0, stream>>>(Apk, Bpk, lsqg, rsqg, outbits);
}